// Round 9
// baseline (77.677 us; speedup 1.0000x reference)
//
#include <hip/hip_runtime.h>

// L1 pairwise distance: out[i][j] = sum_d |x1[i][d] - x2[j][d]|
// x1: [2048, 64] f32, x2: [2048, 64] f32, out: [2048, 2048] f32.
// Mean-adjustment cancels; clamp_min(0) is a no-op on a sum of |.|.
//
// R13 = R12 with the compile fix: __builtin_shufflevector needs LITERAL
// indices -> k-step hoisted into template<int K> (indices 2K,2K+1 are
// compile-time; also scratch-proof by construction, rule #20).
// Theory unchanged from R12: R4(2w/SIMD)=23.4us ~= R11(4w/SIMD)=22.9us
// kernel -> not TLP-bound; pipe-work-bound at derated clock. Cut work:
//  - LDS: f16 tiles -> ds_read_b128 = 8 elems -> 1024 instr/CU (was 2048).
//  - VALU: per 2 elems: v_pk_add_f16(neg) + v_and_b32 0x7FFF7FFF (abs) +
//    v_dot2_f32_f16(|d|,(1,1),acc) = 1.5 instr/elem (was 2), f32 accum.
// Accuracy: threshold 2.18 abs on ~72-magnitude sums; f16 rel err 5e-4 ->
// sum err ~0.05 (30x margin). Accum stays f32.
// Predict: kernel 22.9 -> 13-16us, total 69.4 -> 59-62; absmax <=0.6;
// LDS_Block_Size 18432; no scratch. If total ~69 -> fixed-overhead floor.

#define D_FIXED 64
#define BI 64    // x1 rows per block
#define BJ 64    // x2 cols per block
#define PADH 72  // f16/row: 144B stride -> bank shift 4/row (<=2-way, free), 16B-aligned

typedef _Float16 h2 __attribute__((ext_vector_type(2)));
typedef _Float16 h4 __attribute__((ext_vector_type(4)));
typedef _Float16 h8 __attribute__((ext_vector_type(8)));

#if defined(__has_builtin)
#  if __has_builtin(__builtin_amdgcn_fdot2)
#    define HAVE_FDOT2 1
#  else
#    define HAVE_FDOT2 0
#  endif
#else
#  define HAVE_FDOT2 0
#endif

template <int K>
__device__ __forceinline__ float dotstep(h8 a, h8 b, float sacc, h2 one2) {
    h2 av = __builtin_shufflevector(a, a, 2 * K, 2 * K + 1);   // literal idx
    h2 bv = __builtin_shufflevector(b, b, 2 * K, 2 * K + 1);
    h2 dd = av - bv;                                           // v_pk_add_f16 (neg)
    unsigned u = __builtin_bit_cast(unsigned, dd) & 0x7FFF7FFFu;
    h2 da = __builtin_bit_cast(h2, u);                         // packed |.|
#if HAVE_FDOT2
    return __builtin_amdgcn_fdot2(da, one2, sacc, false);      // v_dot2_f32_f16
#else
    return sacc + (float)da.x + (float)da.y;
#endif
}

__global__ __launch_bounds__(256, 4)
void l1dist_kernel(const float* __restrict__ x1, const float* __restrict__ x2,
                   float* __restrict__ out, int N1, int N2) {
    __shared__ _Float16 s1[BI * PADH];  // 9216 B
    __shared__ _Float16 s2[BJ * PADH];  // 9216 B (18.4KB total)

    const int tx = threadIdx.x;     // 0..15
    const int ty = threadIdx.y;     // 0..15
    const int t  = ty * 16 + tx;
    const int i0 = blockIdx.y * BI;
    const int j0 = blockIdx.x * BJ;

    // ---- one-shot staging: coalesced float4 load, cvt f16, ds_write 8B ----
    const float* g1 = x1 + (size_t)i0 * D_FIXED;
    #pragma unroll
    for (int f = 0; f < 4; ++f) {           // 1024 float4s / 256 threads
        int idx = t + f * 256;
        int row = idx >> 4;
        int c4  = (idx & 15) << 2;
        float4 v = *(const float4*)(g1 + row * D_FIXED + c4);
        h4 h = {(_Float16)v.x, (_Float16)v.y, (_Float16)v.z, (_Float16)v.w};
        *(h4*)(s1 + row * PADH + c4) = h;   // 8B write, 2-way/bank (free)
    }
    const float* g2 = x2 + (size_t)j0 * D_FIXED;
    #pragma unroll
    for (int f = 0; f < 4; ++f) {
        int idx = t + f * 256;
        int row = idx >> 4;
        int c4  = (idx & 15) << 2;
        float4 v = *(const float4*)(g2 + row * D_FIXED + c4);
        h4 h = {(_Float16)v.x, (_Float16)v.y, (_Float16)v.z, (_Float16)v.w};
        *(h4*)(s2 + row * PADH + c4) = h;
    }
    __syncthreads();                         // the ONLY barrier

    // ---- 4x4 register tile: rows i = ty+16r, cols j = tx+16c ----
    float acc[4][4];
    #pragma unroll
    for (int r = 0; r < 4; ++r)
        #pragma unroll
        for (int c = 0; c < 4; ++c) acc[r][c] = 0.0f;

    const h2 one2 = {(_Float16)1.0f, (_Float16)1.0f};

    #pragma unroll
    for (int s = 0; s < 8; ++s) {            // 8 steps x 8 f16 elems
        const int d0 = s * 8;
        h8 a[4], b[4];
        #pragma unroll
        for (int c = 0; c < 4; ++c)          // 16B reads, <=2-way alias (free)
            b[c] = *(const h8*)(s2 + (tx + 16 * c) * PADH + d0);
        #pragma unroll
        for (int r = 0; r < 4; ++r)          // wave-broadcast (4 addrs/wave)
            a[r] = *(const h8*)(s1 + (ty + 16 * r) * PADH + d0);

        #pragma unroll
        for (int r = 0; r < 4; ++r) {
            #pragma unroll
            for (int c = 0; c < 4; ++c) {
                float sacc = acc[r][c];
                sacc = dotstep<0>(a[r], b[c], sacc, one2);
                sacc = dotstep<1>(a[r], b[c], sacc, one2);
                sacc = dotstep<2>(a[r], b[c], sacc, one2);
                sacc = dotstep<3>(a[r], b[c], sacc, one2);
                acc[r][c] = sacc;
            }
        }
    }

    // ---- store: write-once output -> nontemporal; 64B segments per line ----
    #pragma unroll
    for (int r = 0; r < 4; ++r) {
        const size_t i = i0 + ty + 16 * r;
        #pragma unroll
        for (int c = 0; c < 4; ++c) {
            const int j = j0 + tx + 16 * c;
            __builtin_nontemporal_store(acc[r][c], &out[i * N2 + j]);
        }
    }
}

extern "C" void kernel_launch(void* const* d_in, const int* in_sizes, int n_in,
                              void* d_out, int out_size, void* d_ws, size_t ws_size,
                              hipStream_t stream) {
    const float* x1 = (const float*)d_in[0];
    const float* x2 = (const float*)d_in[1];
    float* out = (float*)d_out;

    // in_sizes[] is ELEMENT count (R4/R6-verified): 2048*64 = 131072.
    const int N1 = in_sizes[0] / D_FIXED;  // 2048
    const int N2 = in_sizes[1] / D_FIXED;  // 2048

    dim3 block(16, 16);
    dim3 grid(N2 / BJ, N1 / BI);           // (32, 32) = 1024 blocks = 4/CU
    l1dist_kernel<<<grid, block, 0, stream>>>(x1, x2, out, N1, N2);
}

// Round 11
// 69.922 us; speedup vs baseline: 1.1109x; 1.1109x over previous
//
#include <hip/hip_runtime.h>

// L1 pairwise distance: out[i][j] = sum_d |x1[i][d] - x2[j][d]|
// x1: [2048, 64] f32, x2: [2048, 64] f32, out: [2048, 2048] f32.
// Mean-adjustment cancels; clamp_min(0) is a no-op on a sum of |.|.
//
// R15 = R14 resubmitted verbatim (R10's bench was an infra failure:
// "MI355X container failed twice" -- no compile/correctness signal).
// R14 = R11 (best, 69.39us total) + ONE change: nontemporal stores -> plain
// stores. Evidence trail: R4/R8/R11 (2x occupancy span, 1.33x LDS-work
// span) all land at kernel ~23us +-2%; R13 (halved LDS instrs + 1.5
// VALU/elem via fdot2) got SLOWER (~31us). Kernel time doesn't track pipe
// work; all profiled pipes <=20% busy. Common mechanism with ~10us scale:
// NT stores bypass L2 -> 16.8MB must be accepted by HBM before
// end-of-dispatch, at post-fill derated write rate (in-kernel write BW
// ~0.76 TB/s vs fill's 6.4). But out is only 2.1MB/XCD -> FITS in 4MB L2:
// plain stores write-allocate into L2 and drain lazily AFTER the kernel
// retires.
// Predict: kernel 23 -> 13-17us, total 69.4 -> 62-66 (new best). If
// neutral -> stores exonerated -> declare roofline next round on the
// invariance evidence (fill 41.5 immovable + kernel floor + ~5 overhead).

#define D_FIXED 64
#define BI 64    // x1 rows per block
#define BJ 64    // x2 cols per block
#define PAD 68   // rows 16B-aligned; bank shift 4/row -> <=2-way alias (free, m136)

__global__ __launch_bounds__(256, 4)
void l1dist_kernel(const float* __restrict__ x1, const float* __restrict__ x2,
                   float* __restrict__ out, int N1, int N2) {
    __shared__ float s1[BI * PAD];  // 17408 B
    __shared__ float s2[BJ * PAD];  // 17408 B  (34.8KB total -> 4 blocks/CU)

    const int tx = threadIdx.x;     // 0..15
    const int ty = threadIdx.y;     // 0..15
    const int t  = ty * 16 + tx;
    const int i0 = blockIdx.y * BI;
    const int j0 = blockIdx.x * BJ;

    // ---- one-shot staging (coalesced float4) ----
    const float* g1 = x1 + (size_t)i0 * D_FIXED;
    #pragma unroll
    for (int f = 0; f < 4; ++f) {           // 1024 float4s / 256 threads
        int idx = t + f * 256;
        int row = idx >> 4;
        int c4  = (idx & 15) << 2;
        *(float4*)(s1 + row * PAD + c4) = *(const float4*)(g1 + row * D_FIXED + c4);
    }
    const float* g2 = x2 + (size_t)j0 * D_FIXED;
    #pragma unroll
    for (int f = 0; f < 4; ++f) {           // 1024 float4s / 256 threads
        int idx = t + f * 256;
        int row = idx >> 4;
        int c4  = (idx & 15) << 2;
        *(float4*)(s2 + row * PAD + c4) = *(const float4*)(g2 + row * D_FIXED + c4);
    }
    __syncthreads();                         // the ONLY barrier

    // ---- 4x4 register tile: rows i = ty+16r, cols j = tx+16c ----
    float acc[4][4];
    #pragma unroll
    for (int r = 0; r < 4; ++r)
        #pragma unroll
        for (int c = 0; c < 4; ++c) acc[r][c] = 0.0f;

    #pragma unroll
    for (int d = 0; d < D_FIXED; d += 4) {   // FULL unroll (R3's bound regressed)
        float4 a[4], b[4];
        #pragma unroll
        for (int c = 0; c < 4; ++c)          // <=2-way bank alias (free)
            b[c] = *(const float4*)(s2 + (tx + 16 * c) * PAD + d);
        #pragma unroll
        for (int r = 0; r < 4; ++r)          // wave-broadcast (4 addrs/wave)
            a[r] = *(const float4*)(s1 + (ty + 16 * r) * PAD + d);

        #pragma unroll
        for (int r = 0; r < 4; ++r) {
            #pragma unroll
            for (int c = 0; c < 4; ++c) {
                float d0 = a[r].x - b[c].x;
                float d1 = a[r].y - b[c].y;
                float d2 = a[r].z - b[c].z;
                float d3 = a[r].w - b[c].w;
                // abs folds into v_add_f32 input modifiers: 8 VALU per 4 elems
                acc[r][c] += (fabsf(d0) + fabsf(d1)) + (fabsf(d2) + fabsf(d3));
            }
        }
    }

    // ---- store: PLAIN stores (the one change) -> output lands in L2
    //      (2.1MB/XCD of a 4MB L2); dirty lines drain after retire ----
    #pragma unroll
    for (int r = 0; r < 4; ++r) {
        const size_t i = i0 + ty + 16 * r;
        #pragma unroll
        for (int c = 0; c < 4; ++c) {
            const int j = j0 + tx + 16 * c;
            out[i * N2 + j] = acc[r][c];
        }
    }
}

extern "C" void kernel_launch(void* const* d_in, const int* in_sizes, int n_in,
                              void* d_out, int out_size, void* d_ws, size_t ws_size,
                              hipStream_t stream) {
    const float* x1 = (const float*)d_in[0];
    const float* x2 = (const float*)d_in[1];
    float* out = (float*)d_out;

    // in_sizes[] is ELEMENT count (R4/R6-verified): 2048*64 = 131072.
    const int N1 = in_sizes[0] / D_FIXED;  // 2048
    const int N2 = in_sizes[1] / D_FIXED;  // 2048

    dim3 block(16, 16);
    dim3 grid(N2 / BJ, N1 / BI);           // (32, 32) = 1024 blocks = 4/CU
    l1dist_kernel<<<grid, block, 0, stream>>>(x1, x2, out, N1, N2);
}